// Round 1
// baseline (3025.659 us; speedup 1.0000x reference)
//
#include <hip/hip_runtime.h>
#include <hip/hip_bf16.h>

typedef __bf16 bf16x8 __attribute__((ext_vector_type(8)));
typedef short  short8 __attribute__((ext_vector_type(8)));
typedef float  f32x4  __attribute__((ext_vector_type(4)));

__device__ __forceinline__ short f2bs(float f) {
  return __builtin_bit_cast(short, __float2bfloat16(f));
}

__device__ __forceinline__ bf16x8 ldfrag(const short* p) {
  return *reinterpret_cast<const bf16x8*>(p);
}

// async global->LDS, 16B per lane. lds base must be wave-uniform; HW writes
// base + lane*16 (m104/m108). gaddr is per-lane.
__device__ __forceinline__ void gl2lds16(const short* g, short* lds_base) {
  __builtin_amdgcn_global_load_lds(
      (const __attribute__((address_space(1))) unsigned int*)g,
      (__attribute__((address_space(3))) unsigned int*)lds_base, 16, 0, 0);
}

// ---------------------------------------------------------------------------
// fp32 -> bf16 cast, 8 elements/thread, n % 8 == 0
// ---------------------------------------------------------------------------
__global__ __launch_bounds__(256) void cast8_f32_bf16(const float* __restrict__ in,
                                                      short* __restrict__ out, long n) {
  long i = ((long)blockIdx.x * 256 + threadIdx.x) * 8;
  if (i < n) {
    float4 a = *reinterpret_cast<const float4*>(in + i);
    float4 b = *reinterpret_cast<const float4*>(in + i + 4);
    short8 v;
    v[0] = f2bs(a.x); v[1] = f2bs(a.y); v[2] = f2bs(a.z); v[3] = f2bs(a.w);
    v[4] = f2bs(b.x); v[5] = f2bs(b.y); v[6] = f2bs(b.z); v[7] = f2bs(b.w);
    *reinterpret_cast<short8*>(out + i) = v;
  }
}

// ---------------------------------------------------------------------------
// Deep-pipelined GEMM: C[M,N] = A[M,K](bf16) @ B[N,K](bf16)^T (+bias)
// 256x256 tile, BK=32, 512 thr = 8 waves (2Mx4N), 3-buffer LDS (96 KiB),
// prefetch distance 2 K-tiles, counted s_waitcnt vmcnt(4) (never 0 in loop),
// chunk-XOR LDS swizzle (write side pre-swizzles the GLOBAL source so
// global_load_lds stays linear; read side applies the same XOR), setprio
// around the MFMA cluster, bijective XCD-aware block swizzle.
// Requires M,N % 256 == 0, K % 32 == 0, K >= 64.
// ---------------------------------------------------------------------------
template <typename OT, bool BIAS>
__global__ __launch_bounds__(512, 2)
void gemm_pipe(const short* __restrict__ A, const short* __restrict__ B,
               const float* __restrict__ bias, OT* __restrict__ C,
               int M, int N, int K) {
  __shared__ __align__(16) short As[3][8192];   // 3 x 256 rows x 32 shorts
  __shared__ __align__(16) short Bs[3][8192];

  const int tid  = threadIdx.x;
  const int wave = tid >> 6, lane = tid & 63;
  const int quad = lane >> 4, l16 = lane & 15;
  const int wm = wave >> 2, wn = wave & 3;      // 2 x 4 wave grid

  // XCD-aware bijective swizzle (nwg % 8 == 0 for our shapes: 1280 = 8*160)
  const int nwg = gridDim.x;
  int swz = blockIdx.x;
  if ((nwg & 7) == 0) {
    const int per = nwg >> 3;
    swz = (swz & 7) * per + (swz >> 3);
  }
  const int ntx = N >> 8;
  const int bx = swz % ntx, by = swz / ntx;
  const size_t row0 = (size_t)by << 8, col0 = (size_t)bx << 8;

  // staging: wave w covers rows [w*32, w*32+32) of both tiles, 2 instr each.
  // lane -> LDS chunk c = w*128 + j*64 + lane (16B chunks, linear dest);
  // chunk c holds global (r = c>>2, q = (c&3) ^ (r&3))  [XOR involution/row]
  const int sr = lane >> 2;                     // 0..15 row within 16-row seg
  const int sq = (lane & 3) ^ (sr & 3);         // pre-swizzled global chunk
  const short* Ag0 = A + (row0 + wave * 32 +      sr) * (size_t)K + sq * 8;
  const short* Ag1 = A + (row0 + wave * 32 + 16 + sr) * (size_t)K + sq * 8;
  const short* Bg0 = B + (col0 + wave * 32 +      sr) * (size_t)K + sq * 8;
  const short* Bg1 = B + (col0 + wave * 32 + 16 + sr) * (size_t)K + sq * 8;
  const int lds0 = wave * 1024;                 // shorts

  // read side: global (r, quad) lives at r*32 + (quad ^ (r&3))*8; r&3 == l16&3
  const int aBase = (wm * 128 + l16) * 32 + ((quad ^ (l16 & 3)) * 8);
  const int bBase = (wn * 64  + l16) * 32 + ((quad ^ (l16 & 3)) * 8);

  f32x4 acc[8][4] = {};
  const int NT = K >> 5;

  auto stage = [&](int buf, int t) {
    const int ko = t << 5;
    gl2lds16(Ag0 + ko, &As[buf][lds0]);
    gl2lds16(Ag1 + ko, &As[buf][lds0 + 512]);
    gl2lds16(Bg0 + ko, &Bs[buf][lds0]);
    gl2lds16(Bg1 + ko, &Bs[buf][lds0 + 512]);
  };

  auto compute = [&](int buf) {
    bf16x8 af[8], bv[4];
#pragma unroll
    for (int i = 0; i < 8; i++) af[i] = ldfrag(&As[buf][aBase + i * 512]);
#pragma unroll
    for (int i = 0; i < 4; i++) bv[i] = ldfrag(&Bs[buf][bBase + i * 512]);
    __builtin_amdgcn_s_setprio(1);
#pragma unroll
    for (int mi = 0; mi < 8; mi++)
#pragma unroll
      for (int ni = 0; ni < 4; ni++)
        acc[mi][ni] = __builtin_amdgcn_mfma_f32_16x16x32_bf16(af[mi], bv[ni], acc[mi][ni], 0, 0, 0);
    __builtin_amdgcn_s_setprio(0);
  };

  // prologue: tiles 0,1 in flight; wait only tile 0 (oldest 4 of 8 loads)
  stage(0, 0);
  stage(1, 1);
  asm volatile("s_waitcnt vmcnt(4)" ::: "memory");
  __builtin_amdgcn_s_barrier();
  asm volatile("" ::: "memory");

  for (int t = 0; t < NT; ++t) {
    const int cur = t % 3;
    if (t + 2 < NT) {
      stage((t + 2) % 3, t + 2);   // issue-early; lands 2 K-steps from now
      compute(cur);
      // retire tile t+1's loads (issued last iter, ~full K-step of cover);
      // keep the 4 just-issued tile-(t+2) loads in flight across the barrier
      asm volatile("s_waitcnt vmcnt(4)" ::: "memory");
    } else {
      compute(cur);
      asm volatile("s_waitcnt vmcnt(0)" ::: "memory");  // epilogue drain only
    }
    __builtin_amdgcn_s_barrier();
    asm volatile("" ::: "memory");
    __builtin_amdgcn_sched_barrier(0);
  }

  // D layout per 16x16 frag: row = quad*4 + r, col = l16 (m89-verified)
#pragma unroll
  for (int mi = 0; mi < 8; mi++) {
#pragma unroll
    for (int r = 0; r < 4; r++) {
      const size_t row = row0 + wm * 128 + mi * 16 + quad * 4 + r;
#pragma unroll
      for (int ni = 0; ni < 4; ni++) {
        const size_t col = col0 + wn * 64 + ni * 16 + l16;
        float v = acc[mi][ni][r];
        if constexpr (BIAS) v += bias[col];
        if constexpr (sizeof(OT) == 4)
          C[row * N + col] = v;
        else
          C[row * N + col] = f2bs(v);
      }
    }
  }
}

// ---------------------------------------------------------------------------
// Small guarded GEMM (KV projections only): C = A(fp32) @ B(bf16)^T -> bf16.
// M guarded, inline fp32->bf16 in staging.
// ---------------------------------------------------------------------------
__global__ __launch_bounds__(256)
void gemm_small(const float* __restrict__ A, const short* __restrict__ B,
                short* __restrict__ C, int M, int N, int K) {
  __shared__ short As[128][40];
  __shared__ short Bs[128][40];

  const int tid  = threadIdx.x;
  const int wave = tid >> 6, lane = tid & 63;
  const int quad = lane >> 4, l16 = lane & 15;
  const int wy = wave >> 1, wx = wave & 1;
  const int row0 = blockIdx.y * 128, col0 = blockIdx.x * 128;
  const int sr = tid >> 2;
  const int sc = (tid & 3) * 8;

  f32x4 acc[4][4] = {};

  for (int k0 = 0; k0 < K; k0 += 32) {
    for (int p = 0; p < 128; p += 64) {
      const int r  = sr + p;
      const int gm = row0 + r;
      short8 va = {0, 0, 0, 0, 0, 0, 0, 0};
      if (gm < M) {
        const float* ap = A + (size_t)gm * K + k0 + sc;
        float4 x = *reinterpret_cast<const float4*>(ap);
        float4 y = *reinterpret_cast<const float4*>(ap + 4);
        va[0] = f2bs(x.x); va[1] = f2bs(x.y); va[2] = f2bs(x.z); va[3] = f2bs(x.w);
        va[4] = f2bs(y.x); va[5] = f2bs(y.y); va[6] = f2bs(y.z); va[7] = f2bs(y.w);
      }
      *reinterpret_cast<short8*>(&As[r][sc]) = va;
      *reinterpret_cast<short8*>(&Bs[r][sc]) =
          *reinterpret_cast<const short8*>(B + (size_t)(col0 + r) * K + k0 + sc);
    }
    __syncthreads();

    bf16x8 af[4], bv[4];
#pragma unroll
    for (int i = 0; i < 4; i++) af[i] = ldfrag(&As[wy * 64 + i * 16 + l16][quad * 8]);
#pragma unroll
    for (int i = 0; i < 4; i++) bv[i] = ldfrag(&Bs[wx * 64 + i * 16 + l16][quad * 8]);
#pragma unroll
    for (int mi = 0; mi < 4; mi++)
#pragma unroll
      for (int ni = 0; ni < 4; ni++)
        acc[mi][ni] = __builtin_amdgcn_mfma_f32_16x16x32_bf16(af[mi], bv[ni], acc[mi][ni], 0, 0, 0);
    __syncthreads();
  }

#pragma unroll
  for (int mi = 0; mi < 4; mi++) {
#pragma unroll
    for (int r = 0; r < 4; r++) {
      const int row = row0 + wy * 64 + mi * 16 + quad * 4 + r;
      if (row >= M) continue;
#pragma unroll
      for (int ni = 0; ni < 4; ni++) {
        const int col = col0 + wx * 64 + ni * 16 + l16;
        C[(size_t)row * N + col] = f2bs(acc[mi][ni][r]);
      }
    }
  }
}

// ---------------------------------------------------------------------------
// Fused attention: block = (b, h, 64 q rows); 4 waves x 16 rows.
// ---------------------------------------------------------------------------
__global__ __launch_bounds__(256)
void attn_kernel(const short* __restrict__ Kp, const short* __restrict__ Vp,
                 const short* __restrict__ Qin, short* __restrict__ Oout) {
  __shared__ short Vt[160][104];
  __shared__ short Pl[4][16][104];

  const int tid  = threadIdx.x;
  const int b = blockIdx.z, h = blockIdx.y, s0 = blockIdx.x * 64;
  const int wave = tid >> 6, lane = tid & 63;
  const int quad = lane >> 4, l16 = lane & 15;

  for (int idx = tid; idx < 77 * 160; idx += 256) {
    int t = idx / 160, i = idx - t * 160;
    Vt[i][t] = Vp[((size_t)(b * 77 + t)) * 1280 + h * 160 + i];
  }
  for (int idx = tid; idx < 160 * 19; idx += 256) {
    int i = idx / 19, t = 77 + (idx - i * 19);
    Vt[i][t] = 0;
  }
  __syncthreads();

  const short* Qg = Qin + ((size_t)b * 4096 + s0 + wave * 16 + l16) * 1280 + h * 160;
  bf16x8 qf[5];
#pragma unroll
  for (int kc = 0; kc < 5; kc++) qf[kc] = ldfrag(Qg + kc * 32 + quad * 8);

  f32x4 scv[5];
#pragma unroll
  for (int nt = 0; nt < 5; nt++) {
    f32x4 s = {};
    const short* Kg = Kp + ((size_t)(b * 77) + nt * 16 + l16) * 1280 + h * 160;
#pragma unroll
    for (int kc = 0; kc < 5; kc++) {
      bf16x8 kf = ldfrag(Kg + kc * 32 + quad * 8);
      s = __builtin_amdgcn_mfma_f32_16x16x32_bf16(qf[kc], kf, s, 0, 0, 0);
    }
    scv[nt] = s;
  }

  const float scale = 0.07905694150420949f;  // 160^-0.5
#pragma unroll
  for (int r = 0; r < 4; r++) {
    float v[5];
    float m = -1e30f;
#pragma unroll
    for (int nt = 0; nt < 5; nt++) {
      v[nt] = scv[nt][r];
      if (nt * 16 + l16 < 77) m = fmaxf(m, v[nt]);
    }
#pragma unroll
    for (int off = 1; off < 16; off <<= 1) m = fmaxf(m, __shfl_xor(m, off));
    float sum = 0.f, p[5];
#pragma unroll
    for (int nt = 0; nt < 5; nt++) {
      p[nt] = (nt * 16 + l16 < 77) ? __expf((v[nt] - m) * scale) : 0.f;
      sum += p[nt];
    }
#pragma unroll
    for (int off = 1; off < 16; off <<= 1) sum += __shfl_xor(sum, off);
    const float inv = 1.f / sum;
    const int q = quad * 4 + r;
#pragma unroll
    for (int nt = 0; nt < 5; nt++) Pl[wave][q][nt * 16 + l16] = f2bs(p[nt] * inv);
    Pl[wave][q][80 + l16] = 0;
  }
  __syncthreads();

  bf16x8 pf[3];
#pragma unroll
  for (int kc = 0; kc < 3; kc++) pf[kc] = ldfrag(&Pl[wave][l16][kc * 32 + quad * 8]);

  short* Og = Oout + ((size_t)b * 4096 + s0 + wave * 16) * 1280 + h * 160;
#pragma unroll
  for (int nt = 0; nt < 10; nt++) {
    f32x4 o = {};
#pragma unroll
    for (int kc = 0; kc < 3; kc++) {
      bf16x8 vf = ldfrag(&Vt[nt * 16 + l16][kc * 32 + quad * 8]);
      o = __builtin_amdgcn_mfma_f32_16x16x32_bf16(pf[kc], vf, o, 0, 0, 0);
    }
#pragma unroll
    for (int r = 0; r < 4; r++) {
      const int q = quad * 4 + r;
      Og[(size_t)q * 1280 + nt * 16 + l16] = f2bs(o[r]);
    }
  }
}

// ---------------------------------------------------------------------------
extern "C" void kernel_launch(void* const* d_in, const int* in_sizes, int n_in,
                              void* d_out, int out_size, void* d_ws, size_t ws_size,
                              hipStream_t stream) {
  const float* hs  = (const float*)d_in[0];  // [16,4096,1280]
  const float* enc = (const float*)d_in[1];  // [16,77,768]
  const float* wq  = (const float*)d_in[2];
  const float* wk  = (const float*)d_in[3];
  const float* wv  = (const float*)d_in[4];
  const float* wo  = (const float*)d_in[5];
  const float* bo  = (const float*)d_in[6];
  float* out = (float*)d_out;

  // ws layout (bytes)
  char* ws = (char*)d_ws;
  short* wq_bf = (short*)(ws + 0);          // 1,638,400 el
  short* wk_bf = (short*)(ws + 3276800);    //   983,040 el
  short* wv_bf = (short*)(ws + 5242880);    //   983,040 el
  short* wo_bf = (short*)(ws + 7208960);    // 1,638,400 el
  short* Kp    = (short*)(ws + 10485760);   // 1240 x 1280 (rows >=1232 masked)
  short* Vp    = (short*)(ws + 13660160);   // 1240 x 1280
  short* Xbf   = (short*)(ws + 16834560);   // 65536 x 1280: hs_bf, later attn-out
  if (ws_size < (size_t)184606720) return;

  // bf16 Q buffer parked in d_out (335 MB fp32 >= 167.8 MB bf16; fully
  // overwritten by the final out-projection).
  short* Qb = (short*)d_out;

  cast8_f32_bf16<<<800, 256, 0, stream>>>(wq, wq_bf, 1638400);
  cast8_f32_bf16<<<480, 256, 0, stream>>>(wk, wk_bf, 983040);
  cast8_f32_bf16<<<480, 256, 0, stream>>>(wv, wv_bf, 983040);
  cast8_f32_bf16<<<800, 256, 0, stream>>>(wo, wo_bf, 1638400);
  cast8_f32_bf16<<<40960, 256, 0, stream>>>(hs, Xbf, 83886080);

  // K/V projections: [1232,768] @ [1280,768]^T -> bf16
  dim3 g_kv(10, 10);
  gemm_small<<<g_kv, 256, 0, stream>>>(enc, wk_bf, Kp, 1232, 1280, 768);
  gemm_small<<<g_kv, 256, 0, stream>>>(enc, wv_bf, Vp, 1232, 1280, 768);

  // Q projection: [65536,1280] @ [1280,1280]^T -> bf16 (into d_out scratch)
  // grid: (M/256)*(N/256) = 256*5 = 1280 blocks, 512 threads
  gemm_pipe<short, false><<<1280, 512, 0, stream>>>(Xbf, wq_bf, nullptr, Qb, 65536, 1280, 1280);

  // fused attention: reads Qb (d_out), writes O over Xbf (hs_bf is dead)
  dim3 g_a(64, 8, 16);
  attn_kernel<<<g_a, 256, 0, stream>>>(Kp, Vp, Qb, Xbf);

  // out projection + bias -> fp32 d_out
  gemm_pipe<float, true><<<1280, 512, 0, stream>>>(Xbf, wo_bf, bo, out, 65536, 1280, 1280);
}

// Round 2
// 1722.105 us; speedup vs baseline: 1.7570x; 1.7570x over previous
//
#include <hip/hip_runtime.h>
#include <hip/hip_bf16.h>

typedef __bf16 bf16x8 __attribute__((ext_vector_type(8)));
typedef short  short8 __attribute__((ext_vector_type(8)));
typedef float  f32x4  __attribute__((ext_vector_type(4)));

__device__ __forceinline__ short f2bs(float f) {
  return __builtin_bit_cast(short, __float2bfloat16(f));
}

__device__ __forceinline__ bf16x8 ldfrag(const short* p) {
  return *reinterpret_cast<const bf16x8*>(p);
}

// async global->LDS, 16B per lane. lds base must be wave-uniform; HW writes
// base + lane*16 (m104/m108). gaddr is per-lane.
__device__ __forceinline__ void gl2lds16(const short* g, short* lds_base) {
  __builtin_amdgcn_global_load_lds(
      (const __attribute__((address_space(1))) unsigned int*)g,
      (__attribute__((address_space(3))) unsigned int*)lds_base, 16, 0, 0);
}

// ---------------------------------------------------------------------------
// fp32 -> bf16 cast, 8 elements/thread, n % 8 == 0
// ---------------------------------------------------------------------------
__global__ __launch_bounds__(256) void cast8_f32_bf16(const float* __restrict__ in,
                                                      short* __restrict__ out, long n) {
  long i = ((long)blockIdx.x * 256 + threadIdx.x) * 8;
  if (i < n) {
    float4 a = *reinterpret_cast<const float4*>(in + i);
    float4 b = *reinterpret_cast<const float4*>(in + i + 4);
    short8 v;
    v[0] = f2bs(a.x); v[1] = f2bs(a.y); v[2] = f2bs(a.z); v[3] = f2bs(a.w);
    v[4] = f2bs(b.x); v[5] = f2bs(b.y); v[6] = f2bs(b.z); v[7] = f2bs(b.w);
    *reinterpret_cast<short8*>(out + i) = v;
  }
}

// ---------------------------------------------------------------------------
// Pipelined 128x128 GEMM: C[M,N] = A[M,K](bf16) @ B[N,K](bf16)^T (+bias)
// Same per-thread register profile as the proven 84-VGPR baseline
// (acc[4][4], af[4]/bv[4], 4 waves), plus:
//  - 3 LDS buffers, prefetch distance 2, counted s_waitcnt vmcnt(4) (never 0
//    in the main loop) + single raw s_barrier per K-step (no drain stall)
//  - 2-way bank swizzle: chunk' = chunk ^ ((row>>1)&3), applied on BOTH the
//    pre-swizzled global source (linear global_load_lds dest) and the ds_read
//  - bijective XCD-aware block swizzle (nwg % 8 == 0)
//  - setprio around the MFMA cluster
// Requires M,N % 128 == 0, K % 32 == 0, K >= 64.
// ---------------------------------------------------------------------------
template <typename OT, bool BIAS>
__global__ __launch_bounds__(256)
void gemm_pipe(const short* __restrict__ A, const short* __restrict__ B,
               const float* __restrict__ bias, OT* __restrict__ C,
               int M, int N, int K) {
  __shared__ __align__(16) short As[3][4096];   // 3 x 128 rows x 32 shorts
  __shared__ __align__(16) short Bs[3][4096];

  const int tid  = threadIdx.x;
  const int wave = tid >> 6, lane = tid & 63;
  const int quad = lane >> 4, l16 = lane & 15;
  const int wy = wave >> 1, wx = wave & 1;

  // XCD-aware bijective swizzle (nwg = 5120 = 8*640 for our shapes)
  const int nwg = gridDim.x;
  int swz = blockIdx.x;
  if ((nwg & 7) == 0) swz = (swz & 7) * (nwg >> 3) + (swz >> 3);
  const int ntx = N >> 7;
  const int bx = swz % ntx, by = swz / ntx;
  const size_t row0 = (size_t)by << 7, col0 = (size_t)bx << 7;

  // staging: wave w covers rows [w*32, w*32+32) of both tiles (2 segs each).
  // lane -> LDS (row = seg0 + (lane>>2), chunk = lane&3), 16B chunks, linear
  // dest. Global source chunk is pre-swizzled: gq = (lane&3) ^ ((sr>>1)&3).
  // Segment bases are multiples of 16, so (row>>1)&3 == (sr>>1)&3.
  const int sr = lane >> 2;
  const int gq = (lane & 3) ^ ((sr >> 1) & 3);
  const short* Ag0 = A + (row0 + wave * 32 +      sr) * (size_t)K + gq * 8;
  const short* Ag1 = A + (row0 + wave * 32 + 16 + sr) * (size_t)K + gq * 8;
  const short* Bg0 = B + (col0 + wave * 32 +      sr) * (size_t)K + gq * 8;
  const short* Bg1 = B + (col0 + wave * 32 + 16 + sr) * (size_t)K + gq * 8;

  // read side: global chunk `quad` of row r lives at LDS chunk quad^((r>>1)&3);
  // r = **64 + i*16 + l16  ->  (r>>1)&3 == (l16>>1)&3.
  const int rq = (quad ^ ((l16 >> 1) & 3)) * 8;
  const int aBase = (wy * 64 + l16) * 32 + rq;
  const int bBase = (wx * 64 + l16) * 32 + rq;

  f32x4 acc[4][4] = {};
  const int NT = K >> 5;

  auto stage = [&](int buf, int t) {
    const int ko = t << 5;
    gl2lds16(Ag0 + ko, &As[buf][wave * 1024]);
    gl2lds16(Ag1 + ko, &As[buf][wave * 1024 + 512]);
    gl2lds16(Bg0 + ko, &Bs[buf][wave * 1024]);
    gl2lds16(Bg1 + ko, &Bs[buf][wave * 1024 + 512]);
  };

  auto compute = [&](int buf) {
    bf16x8 af[4], bv[4];
#pragma unroll
    for (int i = 0; i < 4; i++) af[i] = ldfrag(&As[buf][aBase + i * 512]);
#pragma unroll
    for (int i = 0; i < 4; i++) bv[i] = ldfrag(&Bs[buf][bBase + i * 512]);
    __builtin_amdgcn_s_setprio(1);
#pragma unroll
    for (int mi = 0; mi < 4; mi++)
#pragma unroll
      for (int ni = 0; ni < 4; ni++)
        acc[mi][ni] = __builtin_amdgcn_mfma_f32_16x16x32_bf16(af[mi], bv[ni], acc[mi][ni], 0, 0, 0);
    __builtin_amdgcn_s_setprio(0);
  };

  // prologue: tiles 0,1 in flight (8 loads); wait tile 0 (oldest 4)
  stage(0, 0);
  stage(1, 1);
  asm volatile("s_waitcnt vmcnt(4)" ::: "memory");
  __builtin_amdgcn_s_barrier();
  asm volatile("" ::: "memory");

  for (int t = 0; t < NT; ++t) {
    if (t + 2 < NT) {
      stage((t + 2) % 3, t + 2);   // issue-early; consumed 2 K-steps later
      compute(t % 3);
      // retire tile t+1's 4 loads (a full K-step of cover); keep the 4
      // just-issued tile-(t+2) loads in flight across the barrier
      asm volatile("s_waitcnt vmcnt(4)" ::: "memory");
    } else {
      compute(t % 3);
      asm volatile("s_waitcnt vmcnt(0)" ::: "memory");  // tail drain only
    }
    __builtin_amdgcn_s_barrier();
    asm volatile("" ::: "memory");
    __builtin_amdgcn_sched_barrier(0);
  }

  // D layout per 16x16 frag: row = quad*4 + r, col = l16 (m89-verified)
#pragma unroll
  for (int mi = 0; mi < 4; mi++) {
#pragma unroll
    for (int r = 0; r < 4; r++) {
      const size_t row = row0 + wy * 64 + mi * 16 + quad * 4 + r;
#pragma unroll
      for (int ni = 0; ni < 4; ni++) {
        const size_t col = col0 + wx * 64 + ni * 16 + l16;
        float v = acc[mi][ni][r];
        if constexpr (BIAS) v += bias[col];
        if constexpr (sizeof(OT) == 4)
          C[row * N + col] = v;
        else
          C[row * N + col] = f2bs(v);
      }
    }
  }
}

// ---------------------------------------------------------------------------
// Small guarded GEMM (KV projections only): C = A(fp32) @ B(bf16)^T -> bf16.
// M guarded, inline fp32->bf16 in staging.
// ---------------------------------------------------------------------------
__global__ __launch_bounds__(256)
void gemm_small(const float* __restrict__ A, const short* __restrict__ B,
                short* __restrict__ C, int M, int N, int K) {
  __shared__ short As[128][40];
  __shared__ short Bs[128][40];

  const int tid  = threadIdx.x;
  const int wave = tid >> 6, lane = tid & 63;
  const int quad = lane >> 4, l16 = lane & 15;
  const int wy = wave >> 1, wx = wave & 1;
  const int row0 = blockIdx.y * 128, col0 = blockIdx.x * 128;
  const int sr = tid >> 2;
  const int sc = (tid & 3) * 8;

  f32x4 acc[4][4] = {};

  for (int k0 = 0; k0 < K; k0 += 32) {
    for (int p = 0; p < 128; p += 64) {
      const int r  = sr + p;
      const int gm = row0 + r;
      short8 va = {0, 0, 0, 0, 0, 0, 0, 0};
      if (gm < M) {
        const float* ap = A + (size_t)gm * K + k0 + sc;
        float4 x = *reinterpret_cast<const float4*>(ap);
        float4 y = *reinterpret_cast<const float4*>(ap + 4);
        va[0] = f2bs(x.x); va[1] = f2bs(x.y); va[2] = f2bs(x.z); va[3] = f2bs(x.w);
        va[4] = f2bs(y.x); va[5] = f2bs(y.y); va[6] = f2bs(y.z); va[7] = f2bs(y.w);
      }
      *reinterpret_cast<short8*>(&As[r][sc]) = va;
      *reinterpret_cast<short8*>(&Bs[r][sc]) =
          *reinterpret_cast<const short8*>(B + (size_t)(col0 + r) * K + k0 + sc);
    }
    __syncthreads();

    bf16x8 af[4], bv[4];
#pragma unroll
    for (int i = 0; i < 4; i++) af[i] = ldfrag(&As[wy * 64 + i * 16 + l16][quad * 8]);
#pragma unroll
    for (int i = 0; i < 4; i++) bv[i] = ldfrag(&Bs[wx * 64 + i * 16 + l16][quad * 8]);
#pragma unroll
    for (int mi = 0; mi < 4; mi++)
#pragma unroll
      for (int ni = 0; ni < 4; ni++)
        acc[mi][ni] = __builtin_amdgcn_mfma_f32_16x16x32_bf16(af[mi], bv[ni], acc[mi][ni], 0, 0, 0);
    __syncthreads();
  }

#pragma unroll
  for (int mi = 0; mi < 4; mi++) {
#pragma unroll
    for (int r = 0; r < 4; r++) {
      const int row = row0 + wy * 64 + mi * 16 + quad * 4 + r;
      if (row >= M) continue;
#pragma unroll
      for (int ni = 0; ni < 4; ni++) {
        const int col = col0 + wx * 64 + ni * 16 + l16;
        C[(size_t)row * N + col] = f2bs(acc[mi][ni][r]);
      }
    }
  }
}

// ---------------------------------------------------------------------------
// Fused attention: block = (b, h, 64 q rows); 4 waves x 16 rows.
// ---------------------------------------------------------------------------
__global__ __launch_bounds__(256)
void attn_kernel(const short* __restrict__ Kp, const short* __restrict__ Vp,
                 const short* __restrict__ Qin, short* __restrict__ Oout) {
  __shared__ short Vt[160][104];
  __shared__ short Pl[4][16][104];

  const int tid  = threadIdx.x;
  const int b = blockIdx.z, h = blockIdx.y, s0 = blockIdx.x * 64;
  const int wave = tid >> 6, lane = tid & 63;
  const int quad = lane >> 4, l16 = lane & 15;

  for (int idx = tid; idx < 77 * 160; idx += 256) {
    int t = idx / 160, i = idx - t * 160;
    Vt[i][t] = Vp[((size_t)(b * 77 + t)) * 1280 + h * 160 + i];
  }
  for (int idx = tid; idx < 160 * 19; idx += 256) {
    int i = idx / 19, t = 77 + (idx - i * 19);
    Vt[i][t] = 0;
  }
  __syncthreads();

  const short* Qg = Qin + ((size_t)b * 4096 + s0 + wave * 16 + l16) * 1280 + h * 160;
  bf16x8 qf[5];
#pragma unroll
  for (int kc = 0; kc < 5; kc++) qf[kc] = ldfrag(Qg + kc * 32 + quad * 8);

  f32x4 scv[5];
#pragma unroll
  for (int nt = 0; nt < 5; nt++) {
    f32x4 s = {};
    const short* Kg = Kp + ((size_t)(b * 77) + nt * 16 + l16) * 1280 + h * 160;
#pragma unroll
    for (int kc = 0; kc < 5; kc++) {
      bf16x8 kf = ldfrag(Kg + kc * 32 + quad * 8);
      s = __builtin_amdgcn_mfma_f32_16x16x32_bf16(qf[kc], kf, s, 0, 0, 0);
    }
    scv[nt] = s;
  }

  const float scale = 0.07905694150420949f;  // 160^-0.5
#pragma unroll
  for (int r = 0; r < 4; r++) {
    float v[5];
    float m = -1e30f;
#pragma unroll
    for (int nt = 0; nt < 5; nt++) {
      v[nt] = scv[nt][r];
      if (nt * 16 + l16 < 77) m = fmaxf(m, v[nt]);
    }
#pragma unroll
    for (int off = 1; off < 16; off <<= 1) m = fmaxf(m, __shfl_xor(m, off));
    float sum = 0.f, p[5];
#pragma unroll
    for (int nt = 0; nt < 5; nt++) {
      p[nt] = (nt * 16 + l16 < 77) ? __expf((v[nt] - m) * scale) : 0.f;
      sum += p[nt];
    }
#pragma unroll
    for (int off = 1; off < 16; off <<= 1) sum += __shfl_xor(sum, off);
    const float inv = 1.f / sum;
    const int q = quad * 4 + r;
#pragma unroll
    for (int nt = 0; nt < 5; nt++) Pl[wave][q][nt * 16 + l16] = f2bs(p[nt] * inv);
    Pl[wave][q][80 + l16] = 0;
  }
  __syncthreads();

  bf16x8 pf[3];
#pragma unroll
  for (int kc = 0; kc < 3; kc++) pf[kc] = ldfrag(&Pl[wave][l16][kc * 32 + quad * 8]);

  short* Og = Oout + ((size_t)b * 4096 + s0 + wave * 16) * 1280 + h * 160;
#pragma unroll
  for (int nt = 0; nt < 10; nt++) {
    f32x4 o = {};
#pragma unroll
    for (int kc = 0; kc < 3; kc++) {
      bf16x8 vf = ldfrag(&Vt[nt * 16 + l16][kc * 32 + quad * 8]);
      o = __builtin_amdgcn_mfma_f32_16x16x32_bf16(pf[kc], vf, o, 0, 0, 0);
    }
#pragma unroll
    for (int r = 0; r < 4; r++) {
      const int q = quad * 4 + r;
      Og[(size_t)q * 1280 + nt * 16 + l16] = f2bs(o[r]);
    }
  }
}

// ---------------------------------------------------------------------------
extern "C" void kernel_launch(void* const* d_in, const int* in_sizes, int n_in,
                              void* d_out, int out_size, void* d_ws, size_t ws_size,
                              hipStream_t stream) {
  const float* hs  = (const float*)d_in[0];  // [16,4096,1280]
  const float* enc = (const float*)d_in[1];  // [16,77,768]
  const float* wq  = (const float*)d_in[2];
  const float* wk  = (const float*)d_in[3];
  const float* wv  = (const float*)d_in[4];
  const float* wo  = (const float*)d_in[5];
  const float* bo  = (const float*)d_in[6];
  float* out = (float*)d_out;

  // ws layout (bytes)
  char* ws = (char*)d_ws;
  short* wq_bf = (short*)(ws + 0);          // 1,638,400 el
  short* wk_bf = (short*)(ws + 3276800);    //   983,040 el
  short* wv_bf = (short*)(ws + 5242880);    //   983,040 el
  short* wo_bf = (short*)(ws + 7208960);    // 1,638,400 el
  short* Kp    = (short*)(ws + 10485760);   // 1240 x 1280 (rows >=1232 masked)
  short* Vp    = (short*)(ws + 13660160);   // 1240 x 1280
  short* Xbf   = (short*)(ws + 16834560);   // 65536 x 1280: hs_bf, later attn-out
  if (ws_size < (size_t)184606720) return;

  // bf16 Q buffer parked in d_out (335 MB fp32 >= 167.8 MB bf16; fully
  // overwritten by the final out-projection).
  short* Qb = (short*)d_out;

  cast8_f32_bf16<<<800, 256, 0, stream>>>(wq, wq_bf, 1638400);
  cast8_f32_bf16<<<480, 256, 0, stream>>>(wk, wk_bf, 983040);
  cast8_f32_bf16<<<480, 256, 0, stream>>>(wv, wv_bf, 983040);
  cast8_f32_bf16<<<800, 256, 0, stream>>>(wo, wo_bf, 1638400);
  cast8_f32_bf16<<<40960, 256, 0, stream>>>(hs, Xbf, 83886080);

  // K/V projections: [1232,768] @ [1280,768]^T -> bf16
  dim3 g_kv(10, 10);
  gemm_small<<<g_kv, 256, 0, stream>>>(enc, wk_bf, Kp, 1232, 1280, 768);
  gemm_small<<<g_kv, 256, 0, stream>>>(enc, wv_bf, Vp, 1232, 1280, 768);

  // Q projection: [65536,1280] @ [1280,1280]^T -> bf16 (into d_out scratch)
  // grid: (N/128)*(M/128) = 10*512 = 5120 blocks (flattened, XCD-swizzled)
  gemm_pipe<short, false><<<5120, 256, 0, stream>>>(Xbf, wq_bf, nullptr, Qb, 65536, 1280, 1280);

  // fused attention: reads Qb (d_out), writes O over Xbf (hs_bf is dead)
  dim3 g_a(64, 8, 16);
  attn_kernel<<<g_a, 256, 0, stream>>>(Kp, Vp, Qb, Xbf);

  // out projection + bias -> fp32 d_out
  gemm_pipe<float, true><<<5120, 256, 0, stream>>>(Xbf, wo_bf, bo, out, 65536, 1280, 1280);
}

// Round 3
// 1712.087 us; speedup vs baseline: 1.7672x; 1.0059x over previous
//
#include <hip/hip_runtime.h>
#include <hip/hip_bf16.h>

typedef __bf16 bf16x8 __attribute__((ext_vector_type(8)));
typedef short  short8 __attribute__((ext_vector_type(8)));
typedef float  f32x4  __attribute__((ext_vector_type(4)));

__device__ __forceinline__ short f2bs(float f) {
  return __builtin_bit_cast(short, __float2bfloat16(f));
}

__device__ __forceinline__ bf16x8 ldfrag(const short* p) {
  return *reinterpret_cast<const bf16x8*>(p);
}

// async global->LDS, 16B per lane. lds base must be wave-uniform; HW writes
// base + lane*16 (m104/m108). gaddr is per-lane.
__device__ __forceinline__ void gl2lds16(const short* g, short* lds_base) {
  __builtin_amdgcn_global_load_lds(
      (const __attribute__((address_space(1))) unsigned int*)g,
      (__attribute__((address_space(3))) unsigned int*)lds_base, 16, 0, 0);
}

// ---------------------------------------------------------------------------
// fp32 -> bf16 cast, 8 elements/thread, n % 8 == 0
// ---------------------------------------------------------------------------
__global__ __launch_bounds__(256) void cast8_f32_bf16(const float* __restrict__ in,
                                                      short* __restrict__ out, long n) {
  long i = ((long)blockIdx.x * 256 + threadIdx.x) * 8;
  if (i < n) {
    float4 a = *reinterpret_cast<const float4*>(in + i);
    float4 b = *reinterpret_cast<const float4*>(in + i + 4);
    short8 v;
    v[0] = f2bs(a.x); v[1] = f2bs(a.y); v[2] = f2bs(a.z); v[3] = f2bs(a.w);
    v[4] = f2bs(b.x); v[5] = f2bs(b.y); v[6] = f2bs(b.z); v[7] = f2bs(b.w);
    *reinterpret_cast<short8*>(out + i) = v;
  }
}

// ---------------------------------------------------------------------------
// Pipelined 128x128 GEMM: C[M,N] = A[M,K](bf16) @ B[N,K](bf16)^T (+bias)
// Identical to Round-2 kernel EXCEPT: the per-iteration sched_barrier(0) is
// REMOVED (m141 pathology: order-pinning defeats compiler scheduling, -42%).
//  - 3 LDS buffers, prefetch distance 2, counted s_waitcnt vmcnt(4) (never 0
//    in the main loop) + single raw s_barrier per K-step (no drain stall)
//  - 2-way bank swizzle: chunk' = chunk ^ ((row>>1)&3), both-sides
//    (pre-swizzled global source, linear global_load_lds dest, XOR'd ds_read)
//    -> SQ_LDS_BANK_CONFLICT == 0 (measured R2)
//  - bijective XCD-aware block swizzle (nwg % 8 == 0) -> FETCH 768->220 MB
//  - setprio around the MFMA cluster
// Requires M,N % 128 == 0, K % 32 == 0, K >= 64.
// ---------------------------------------------------------------------------
template <typename OT, bool BIAS>
__global__ __launch_bounds__(256)
void gemm_pipe(const short* __restrict__ A, const short* __restrict__ B,
               const float* __restrict__ bias, OT* __restrict__ C,
               int M, int N, int K) {
  __shared__ __align__(16) short As[3][4096];   // 3 x 128 rows x 32 shorts
  __shared__ __align__(16) short Bs[3][4096];

  const int tid  = threadIdx.x;
  const int wave = tid >> 6, lane = tid & 63;
  const int quad = lane >> 4, l16 = lane & 15;
  const int wy = wave >> 1, wx = wave & 1;

  // XCD-aware bijective swizzle (nwg = 5120 = 8*640 for our shapes)
  const int nwg = gridDim.x;
  int swz = blockIdx.x;
  if ((nwg & 7) == 0) swz = (swz & 7) * (nwg >> 3) + (swz >> 3);
  const int ntx = N >> 7;
  const int bx = swz % ntx, by = swz / ntx;
  const size_t row0 = (size_t)by << 7, col0 = (size_t)bx << 7;

  // staging: wave w covers rows [w*32, w*32+32) of both tiles (2 segs each).
  // lane -> LDS (row = seg0 + (lane>>2), chunk = lane&3), 16B chunks, linear
  // dest. Global source chunk is pre-swizzled: gq = (lane&3) ^ ((sr>>1)&3).
  // Segment bases are multiples of 16, so (row>>1)&3 == (sr>>1)&3.
  const int sr = lane >> 2;
  const int gq = (lane & 3) ^ ((sr >> 1) & 3);
  const short* Ag0 = A + (row0 + wave * 32 +      sr) * (size_t)K + gq * 8;
  const short* Ag1 = A + (row0 + wave * 32 + 16 + sr) * (size_t)K + gq * 8;
  const short* Bg0 = B + (col0 + wave * 32 +      sr) * (size_t)K + gq * 8;
  const short* Bg1 = B + (col0 + wave * 32 + 16 + sr) * (size_t)K + gq * 8;

  // read side: global chunk `quad` of row r lives at LDS chunk quad^((r>>1)&3);
  // r = **64 + i*16 + l16  ->  (r>>1)&3 == (l16>>1)&3.
  const int rq = (quad ^ ((l16 >> 1) & 3)) * 8;
  const int aBase = (wy * 64 + l16) * 32 + rq;
  const int bBase = (wx * 64 + l16) * 32 + rq;

  f32x4 acc[4][4] = {};
  const int NT = K >> 5;

  auto stage = [&](int buf, int t) {
    const int ko = t << 5;
    gl2lds16(Ag0 + ko, &As[buf][wave * 1024]);
    gl2lds16(Ag1 + ko, &As[buf][wave * 1024 + 512]);
    gl2lds16(Bg0 + ko, &Bs[buf][wave * 1024]);
    gl2lds16(Bg1 + ko, &Bs[buf][wave * 1024 + 512]);
  };

  auto compute = [&](int buf) {
    bf16x8 af[4], bv[4];
#pragma unroll
    for (int i = 0; i < 4; i++) af[i] = ldfrag(&As[buf][aBase + i * 512]);
#pragma unroll
    for (int i = 0; i < 4; i++) bv[i] = ldfrag(&Bs[buf][bBase + i * 512]);
    __builtin_amdgcn_s_setprio(1);
#pragma unroll
    for (int mi = 0; mi < 4; mi++)
#pragma unroll
      for (int ni = 0; ni < 4; ni++)
        acc[mi][ni] = __builtin_amdgcn_mfma_f32_16x16x32_bf16(af[mi], bv[ni], acc[mi][ni], 0, 0, 0);
    __builtin_amdgcn_s_setprio(0);
  };

  // prologue: tiles 0,1 in flight (8 loads); wait tile 0 (oldest 4)
  stage(0, 0);
  stage(1, 1);
  asm volatile("s_waitcnt vmcnt(4)" ::: "memory");
  __builtin_amdgcn_s_barrier();
  asm volatile("" ::: "memory");

  for (int t = 0; t < NT; ++t) {
    if (t + 2 < NT) {
      stage((t + 2) % 3, t + 2);   // issue-early; consumed 2 K-steps later
      compute(t % 3);
      // retire tile t+1's 4 loads (a full K-step of cover); keep the 4
      // just-issued tile-(t+2) loads in flight across the barrier
      asm volatile("s_waitcnt vmcnt(4)" ::: "memory");
    } else {
      compute(t % 3);
      asm volatile("s_waitcnt vmcnt(0)" ::: "memory");  // tail drain only
    }
    __builtin_amdgcn_s_barrier();
    asm volatile("" ::: "memory");
  }

  // D layout per 16x16 frag: row = quad*4 + r, col = l16 (m89-verified)
#pragma unroll
  for (int mi = 0; mi < 4; mi++) {
#pragma unroll
    for (int r = 0; r < 4; r++) {
      const size_t row = row0 + wy * 64 + mi * 16 + quad * 4 + r;
#pragma unroll
      for (int ni = 0; ni < 4; ni++) {
        const size_t col = col0 + wx * 64 + ni * 16 + l16;
        float v = acc[mi][ni][r];
        if constexpr (BIAS) v += bias[col];
        if constexpr (sizeof(OT) == 4)
          C[row * N + col] = v;
        else
          C[row * N + col] = f2bs(v);
      }
    }
  }
}

// ---------------------------------------------------------------------------
// Small guarded GEMM (KV projections only): C = A(fp32) @ B(bf16)^T -> bf16.
// M guarded, inline fp32->bf16 in staging.
// ---------------------------------------------------------------------------
__global__ __launch_bounds__(256)
void gemm_small(const float* __restrict__ A, const short* __restrict__ B,
                short* __restrict__ C, int M, int N, int K) {
  __shared__ short As[128][40];
  __shared__ short Bs[128][40];

  const int tid  = threadIdx.x;
  const int wave = tid >> 6, lane = tid & 63;
  const int quad = lane >> 4, l16 = lane & 15;
  const int wy = wave >> 1, wx = wave & 1;
  const int row0 = blockIdx.y * 128, col0 = blockIdx.x * 128;
  const int sr = tid >> 2;
  const int sc = (tid & 3) * 8;

  f32x4 acc[4][4] = {};

  for (int k0 = 0; k0 < K; k0 += 32) {
    for (int p = 0; p < 128; p += 64) {
      const int r  = sr + p;
      const int gm = row0 + r;
      short8 va = {0, 0, 0, 0, 0, 0, 0, 0};
      if (gm < M) {
        const float* ap = A + (size_t)gm * K + k0 + sc;
        float4 x = *reinterpret_cast<const float4*>(ap);
        float4 y = *reinterpret_cast<const float4*>(ap + 4);
        va[0] = f2bs(x.x); va[1] = f2bs(x.y); va[2] = f2bs(x.z); va[3] = f2bs(x.w);
        va[4] = f2bs(y.x); va[5] = f2bs(y.y); va[6] = f2bs(y.z); va[7] = f2bs(y.w);
      }
      *reinterpret_cast<short8*>(&As[r][sc]) = va;
      *reinterpret_cast<short8*>(&Bs[r][sc]) =
          *reinterpret_cast<const short8*>(B + (size_t)(col0 + r) * K + k0 + sc);
    }
    __syncthreads();

    bf16x8 af[4], bv[4];
#pragma unroll
    for (int i = 0; i < 4; i++) af[i] = ldfrag(&As[wy * 64 + i * 16 + l16][quad * 8]);
#pragma unroll
    for (int i = 0; i < 4; i++) bv[i] = ldfrag(&Bs[wx * 64 + i * 16 + l16][quad * 8]);
#pragma unroll
    for (int mi = 0; mi < 4; mi++)
#pragma unroll
      for (int ni = 0; ni < 4; ni++)
        acc[mi][ni] = __builtin_amdgcn_mfma_f32_16x16x32_bf16(af[mi], bv[ni], acc[mi][ni], 0, 0, 0);
    __syncthreads();
  }

#pragma unroll
  for (int mi = 0; mi < 4; mi++) {
#pragma unroll
    for (int r = 0; r < 4; r++) {
      const int row = row0 + wy * 64 + mi * 16 + quad * 4 + r;
      if (row >= M) continue;
#pragma unroll
      for (int ni = 0; ni < 4; ni++) {
        const int col = col0 + wx * 64 + ni * 16 + l16;
        C[(size_t)row * N + col] = f2bs(acc[mi][ni][r]);
      }
    }
  }
}

// ---------------------------------------------------------------------------
// Fused attention: block = (b, h, 64 q rows); 4 waves x 16 rows.
// ---------------------------------------------------------------------------
__global__ __launch_bounds__(256)
void attn_kernel(const short* __restrict__ Kp, const short* __restrict__ Vp,
                 const short* __restrict__ Qin, short* __restrict__ Oout) {
  __shared__ short Vt[160][104];
  __shared__ short Pl[4][16][104];

  const int tid  = threadIdx.x;
  const int b = blockIdx.z, h = blockIdx.y, s0 = blockIdx.x * 64;
  const int wave = tid >> 6, lane = tid & 63;
  const int quad = lane >> 4, l16 = lane & 15;

  for (int idx = tid; idx < 77 * 160; idx += 256) {
    int t = idx / 160, i = idx - t * 160;
    Vt[i][t] = Vp[((size_t)(b * 77 + t)) * 1280 + h * 160 + i];
  }
  for (int idx = tid; idx < 160 * 19; idx += 256) {
    int i = idx / 19, t = 77 + (idx - i * 19);
    Vt[i][t] = 0;
  }
  __syncthreads();

  const short* Qg = Qin + ((size_t)b * 4096 + s0 + wave * 16 + l16) * 1280 + h * 160;
  bf16x8 qf[5];
#pragma unroll
  for (int kc = 0; kc < 5; kc++) qf[kc] = ldfrag(Qg + kc * 32 + quad * 8);

  f32x4 scv[5];
#pragma unroll
  for (int nt = 0; nt < 5; nt++) {
    f32x4 s = {};
    const short* Kg = Kp + ((size_t)(b * 77) + nt * 16 + l16) * 1280 + h * 160;
#pragma unroll
    for (int kc = 0; kc < 5; kc++) {
      bf16x8 kf = ldfrag(Kg + kc * 32 + quad * 8);
      s = __builtin_amdgcn_mfma_f32_16x16x32_bf16(qf[kc], kf, s, 0, 0, 0);
    }
    scv[nt] = s;
  }

  const float scale = 0.07905694150420949f;  // 160^-0.5
#pragma unroll
  for (int r = 0; r < 4; r++) {
    float v[5];
    float m = -1e30f;
#pragma unroll
    for (int nt = 0; nt < 5; nt++) {
      v[nt] = scv[nt][r];
      if (nt * 16 + l16 < 77) m = fmaxf(m, v[nt]);
    }
#pragma unroll
    for (int off = 1; off < 16; off <<= 1) m = fmaxf(m, __shfl_xor(m, off));
    float sum = 0.f, p[5];
#pragma unroll
    for (int nt = 0; nt < 5; nt++) {
      p[nt] = (nt * 16 + l16 < 77) ? __expf((v[nt] - m) * scale) : 0.f;
      sum += p[nt];
    }
#pragma unroll
    for (int off = 1; off < 16; off <<= 1) sum += __shfl_xor(sum, off);
    const float inv = 1.f / sum;
    const int q = quad * 4 + r;
#pragma unroll
    for (int nt = 0; nt < 5; nt++) Pl[wave][q][nt * 16 + l16] = f2bs(p[nt] * inv);
    Pl[wave][q][80 + l16] = 0;
  }
  __syncthreads();

  bf16x8 pf[3];
#pragma unroll
  for (int kc = 0; kc < 3; kc++) pf[kc] = ldfrag(&Pl[wave][l16][kc * 32 + quad * 8]);

  short* Og = Oout + ((size_t)b * 4096 + s0 + wave * 16) * 1280 + h * 160;
#pragma unroll
  for (int nt = 0; nt < 10; nt++) {
    f32x4 o = {};
#pragma unroll
    for (int kc = 0; kc < 3; kc++) {
      bf16x8 vf = ldfrag(&Vt[nt * 16 + l16][kc * 32 + quad * 8]);
      o = __builtin_amdgcn_mfma_f32_16x16x32_bf16(pf[kc], vf, o, 0, 0, 0);
    }
#pragma unroll
    for (int r = 0; r < 4; r++) {
      const int q = quad * 4 + r;
      Og[(size_t)q * 1280 + nt * 16 + l16] = f2bs(o[r]);
    }
  }
}

// ---------------------------------------------------------------------------
extern "C" void kernel_launch(void* const* d_in, const int* in_sizes, int n_in,
                              void* d_out, int out_size, void* d_ws, size_t ws_size,
                              hipStream_t stream) {
  const float* hs  = (const float*)d_in[0];  // [16,4096,1280]
  const float* enc = (const float*)d_in[1];  // [16,77,768]
  const float* wq  = (const float*)d_in[2];
  const float* wk  = (const float*)d_in[3];
  const float* wv  = (const float*)d_in[4];
  const float* wo  = (const float*)d_in[5];
  const float* bo  = (const float*)d_in[6];
  float* out = (float*)d_out;

  // ws layout (bytes)
  char* ws = (char*)d_ws;
  short* wq_bf = (short*)(ws + 0);          // 1,638,400 el
  short* wk_bf = (short*)(ws + 3276800);    //   983,040 el
  short* wv_bf = (short*)(ws + 5242880);    //   983,040 el
  short* wo_bf = (short*)(ws + 7208960);    // 1,638,400 el
  short* Kp    = (short*)(ws + 10485760);   // 1240 x 1280 (rows >=1232 masked)
  short* Vp    = (short*)(ws + 13660160);   // 1240 x 1280
  short* Xbf   = (short*)(ws + 16834560);   // 65536 x 1280: hs_bf, later attn-out
  if (ws_size < (size_t)184606720) return;

  // bf16 Q buffer parked in d_out (335 MB fp32 >= 167.8 MB bf16; fully
  // overwritten by the final out-projection).
  short* Qb = (short*)d_out;

  cast8_f32_bf16<<<800, 256, 0, stream>>>(wq, wq_bf, 1638400);
  cast8_f32_bf16<<<480, 256, 0, stream>>>(wk, wk_bf, 983040);
  cast8_f32_bf16<<<480, 256, 0, stream>>>(wv, wv_bf, 983040);
  cast8_f32_bf16<<<800, 256, 0, stream>>>(wo, wo_bf, 1638400);
  cast8_f32_bf16<<<40960, 256, 0, stream>>>(hs, Xbf, 83886080);

  // K/V projections: [1232,768] @ [1280,768]^T -> bf16
  dim3 g_kv(10, 10);
  gemm_small<<<g_kv, 256, 0, stream>>>(enc, wk_bf, Kp, 1232, 1280, 768);
  gemm_small<<<g_kv, 256, 0, stream>>>(enc, wv_bf, Vp, 1232, 1280, 768);

  // Q projection: [65536,1280] @ [1280,1280]^T -> bf16 (into d_out scratch)
  // grid: (N/128)*(M/128) = 10*512 = 5120 blocks (flattened, XCD-swizzled)
  gemm_pipe<short, false><<<5120, 256, 0, stream>>>(Xbf, wq_bf, nullptr, Qb, 65536, 1280, 1280);

  // fused attention: reads Qb (d_out), writes O over Xbf (hs_bf is dead)
  dim3 g_a(64, 8, 16);
  attn_kernel<<<g_a, 256, 0, stream>>>(Kp, Vp, Qb, Xbf);

  // out projection + bias -> fp32 d_out
  gemm_pipe<float, true><<<5120, 256, 0, stream>>>(Xbf, wo_bf, bo, out, 65536, 1280, 1280);
}